// Round 2
// baseline (1239.032 us; speedup 1.0000x reference)
//
#include <hip/hip_runtime.h>
#include <stdint.h>
#include <stddef.h>

#define N_TOK 8192
#define DIM   1024
#define NE    8
#define NF    4096
#define TM    256                 /* M-pad granularity (matches BM) */
#define BKK   64
#define RCAP  (N_TOK*2 + NE*TM)   /* 18432 padded assignment rows */
#define MAXMT (N_TOK/TM)          /* 32 worst-case m-tiles per expert */
#define KS2   2                   /* ffn2 K-split */

typedef __attribute__((ext_vector_type(8))) short short8;
typedef __attribute__((ext_vector_type(4))) float f32x4;

__device__ __forceinline__ float bf2f(short s){
  unsigned u = ((unsigned)(unsigned short)s) << 16;
  return __builtin_bit_cast(float, u);
}
__device__ __forceinline__ short f2bf(float f){
  unsigned u = __builtin_bit_cast(unsigned, f);
  u += 0x7fffu + ((u >> 16) & 1u);   // RNE (inputs are tame, no NaN)
  return (short)(u >> 16);
}

#define GLD_LDS16(g, l) __builtin_amdgcn_global_load_lds( \
    (const __attribute__((address_space(1))) void*)(g),   \
    (__attribute__((address_space(3))) void*)(l), 16, 0, 0)

// bijective XCD-chunk swizzle (nwg % 8 == 0 for both ffn grids)
__device__ __forceinline__ void xcd_map(int nx, int& xo, int& mt, int& e){
  int h   = blockIdx.x + nx * (blockIdx.y + MAXMT * blockIdx.z);
  int nwg = nx * MAXMT * NE;
  int q   = nwg >> 3;
  int wk  = (h & 7) * q + (h >> 3);
  xo = wk % nx;
  int r = wk / nx;
  mt = r % MAXMT;
  e  = r / MAXMT;
}

// ---------------- gating (pure fp32: selection must match reference) --------
__global__ __launch_bounds__(256) void gate_kernel(
    const float* __restrict__ x, const float* __restrict__ gw,
    int* __restrict__ topi, float* __restrict__ gatev, int* __restrict__ ctrl)
{
  int t = blockIdx.x * 4 + (threadIdx.x >> 6);
  int lane = threadIdx.x & 63;
  const float* xr = x + (size_t)t * DIM;
  float p[NE];
  #pragma unroll
  for (int e = 0; e < NE; e++) p[e] = 0.f;
  for (int i = lane; i < DIM; i += 64){
    float xv = xr[i];
    const float* g = gw + i * NE;
    #pragma unroll
    for (int e = 0; e < NE; e++) p[e] += xv * g[e];
  }
  #pragma unroll
  for (int off = 32; off > 0; off >>= 1){
    #pragma unroll
    for (int e = 0; e < NE; e++) p[e] += __shfl_xor(p[e], off, 64);
  }
  if (lane == 0){
    int i1 = 0; float v1 = p[0];
    #pragma unroll
    for (int e = 1; e < NE; e++) if (p[e] > v1){ v1 = p[e]; i1 = e; }
    int i2 = -1; float v2 = -3.4e38f;
    #pragma unroll
    for (int e = 0; e < NE; e++) if (e != i1 && p[e] > v2){ v2 = p[e]; i2 = e; }
    float ex = expf(v2 - v1);          // v1 >= v2
    float g2 = ex / (1.f + ex);
    float g1 = 1.f - g2;
    topi[t*2]   = i1;  topi[t*2+1]  = i2;
    gatev[t*2]  = g1;  gatev[t*2+1] = g2;
    atomicAdd(&ctrl[i1], 1);
    atomicAdd(&ctrl[i2], 1);
  }
}

// ctrl ints: [0..7]=counts  [8..15]=cursors  [16..23]=offs  [24..31]=caps
__global__ void scan_kernel(int* ctrl){
  if (threadIdx.x == 0){
    int tot = 0;
    for (int e = 0; e < NE; e++){
      int c = ctrl[e];
      int cap = (c + TM - 1) & ~(TM - 1);
      ctrl[16+e] = tot; ctrl[24+e] = cap; tot += cap;
    }
  }
}

__global__ __launch_bounds__(256) void scatter_kernel(
    const int* __restrict__ topi, int* ctrl,
    int* __restrict__ rowTok, int* __restrict__ tok2row)
{
  int t = blockIdx.x * 256 + threadIdx.x;
  #pragma unroll
  for (int k = 0; k < 2; k++){
    int e = topi[t*2 + k];
    int pos = atomicAdd(&ctrl[8+e], 1);
    int r = ctrl[16+e] + pos;
    rowTok[r] = t;
    tok2row[t*2 + k] = r;
  }
}

__global__ void pad_kernel(const int* __restrict__ ctrl, int* __restrict__ rowTok){
  int e = blockIdx.x;
  int cnt = ctrl[e], cap = ctrl[24+e], off = ctrl[16+e];
  for (int i = cnt + threadIdx.x; i < cap; i += blockDim.x)
    rowTok[off + i] = N_TOK;    // sentinel -> zero row of Xb
}

// ---------------- casts -----------------------------------------------------
__global__ __launch_bounds__(256) void cast_x_kernel(
    const float* __restrict__ x, short* __restrict__ xb)
{
  size_t i = ((size_t)blockIdx.x * 256 + threadIdx.x) * 8;
  if (i >= (size_t)(N_TOK + 1) * DIM) return;
  short8 o;
  if (i < (size_t)N_TOK * DIM){
    #pragma unroll
    for (int j = 0; j < 8; j++) o[j] = f2bf(x[i + j]);
  } else {
    #pragma unroll
    for (int j = 0; j < 8; j++) o[j] = 0;
  }
  *(short8*)(xb + i) = o;
}

// src[e][k][n] fp32 -> dst[e][n][k] bf16, LDS-tiled 64x64 transpose.
__global__ __launch_bounds__(256) void transpose_cast_kernel(
    const float* __restrict__ src, short* __restrict__ dst, int Kd, int Nd)
{
  __shared__ float Ls[64][65];
  int e = blockIdx.z;
  int k0 = blockIdx.y * 64, n0 = blockIdx.x * 64;
  const float* s = src + (size_t)e * Kd * Nd;
  short*       d = dst + (size_t)e * Kd * Nd;
  int t = threadIdx.x;
  int kr = t >> 4, nc = (t & 15) * 4;
  #pragma unroll
  for (int rr = 0; rr < 4; rr++){
    int k = rr*16 + kr;
    f32x4 v = *(const f32x4*)(s + (size_t)(k0 + k) * Nd + n0 + nc);
    Ls[k][nc+0] = v[0]; Ls[k][nc+1] = v[1];
    Ls[k][nc+2] = v[2]; Ls[k][nc+3] = v[3];
  }
  __syncthreads();
  int nr = t >> 2, kc = (t & 3) * 16;
  short o[16];
  #pragma unroll
  for (int i = 0; i < 16; i++) o[i] = f2bf(Ls[kc + i][nr]);
  short* dp = d + (size_t)(n0 + nr) * Kd + k0 + kc;
  *(short8*)(dp)     = *(short8*)&o[0];
  *(short8*)(dp + 8) = *(short8*)&o[8];
}

// ============ grouped GEMM, 256x256 tile, 8 waves, quadrant phases ==========
// LDS XOR swizzle: physical 16B chunk p of row r holds logical chunk p^(r&7)
// (source address pre-swizzled; global_load_lds dest stays linear).
// Schedule: 4 quadrant phases (raw s_barrier each) + boundary:
//   barrier; issue tile t+2 -> slot (t&1); vmcnt(8) [tile t+1 landed]; barrier.
// vmcnt never drains to 0 mid-loop (T4).

#define FFN_DECLS                                                       \
  __shared__ __align__(16) short As[2][256][BKK];                       \
  __shared__ __align__(16) short Bs[2][256][BKK];                       \
  int tid = threadIdx.x, w = tid >> 6, lane = tid & 63;                 \
  int rsub = lane >> 3, ksub = lane & 7;                                \
  int sw = (ksub ^ rsub) * 8;                                           \
  char* const AsB = (char*)As; char* const BsB = (char*)Bs;             \
  int ml = lane & 15, q = lane >> 4;                                    \
  int wm = w >> 2, wn = w & 3;                                          \
  int mx = ml & 7;                                                      \
  f32x4 acc[8][4];                                                      \
  _Pragma("unroll")                                                     \
  for (int i = 0; i < 8; i++){                                          \
    _Pragma("unroll")                                                   \
    for (int j = 0; j < 4; j++){ f32x4 z = {0.f,0.f,0.f,0.f}; acc[i][j] = z; } \
  }

#define FFN_STAGE(kt, s) do{                                            \
    char* aB_ = AsB + (s)*32768; char* bB_ = BsB + (s)*32768;           \
    _Pragma("unroll")                                                   \
    for (int j = 0; j < 4; j++) GLD_LDS16(ap[j] + (kt)*BKK, aB_ + (w*4+j)*1024); \
    _Pragma("unroll")                                                   \
    for (int j = 0; j < 4; j++) GLD_LDS16(bp[j] + (kt)*BKK, bB_ + (w*4+j)*1024); \
  } while(0)

#define FFN_PROLOGUE                                                    \
  FFN_STAGE(0, 0);                                                      \
  FFN_STAGE(1, 1);                                                      \
  asm volatile("s_waitcnt vmcnt(8)" ::: "memory");                      \
  __builtin_amdgcn_sched_barrier(0);                                    \
  __builtin_amdgcn_s_barrier();

#define LDA(mh)                                                         \
  _Pragma("unroll")                                                     \
  for (int mi = 0; mi < 4; mi++){                                       \
    _Pragma("unroll")                                                   \
    for (int ks = 0; ks < 2; ks++)                                      \
      aq[mi][ks] = Ar[(wm*128 + (mh)*64 + mi*16 + ml)*8 + ((ks*4+q)^mx)]; \
  }

#define LDB_ALL                                                         \
  _Pragma("unroll")                                                     \
  for (int ni = 0; ni < 4; ni++){                                       \
    _Pragma("unroll")                                                   \
    for (int ks = 0; ks < 2; ks++)                                      \
      bq[ni][ks] = Br[(wn*64 + ni*16 + ml)*8 + ((ks*4+q)^mx)];          \
  }

#define MFMA_Q(mh, nh)                                                  \
  __builtin_amdgcn_s_barrier();                                         \
  __builtin_amdgcn_s_setprio(1);                                        \
  _Pragma("unroll")                                                     \
  for (int mi = 0; mi < 4; mi++){                                       \
    _Pragma("unroll")                                                   \
    for (int ni = 0; ni < 2; ni++){                                     \
      _Pragma("unroll")                                                 \
      for (int ks = 0; ks < 2; ks++)                                    \
        acc[(mh)*4+mi][(nh)*2+ni] = __builtin_amdgcn_mfma_f32_16x16x32_bf16( \
            aq[mi][ks], bq[(nh)*2+ni][ks], acc[(mh)*4+mi][(nh)*2+ni], 0, 0, 0); \
    }                                                                   \
  }                                                                     \
  __builtin_amdgcn_s_setprio(0);

#define FFN_ITER_BODY(s)                                                \
  const short8* Ar = (const short8*)(AsB + (s)*32768);                  \
  const short8* Br = (const short8*)(BsB + (s)*32768);                  \
  LDA(0); LDB_ALL;                                                      \
  MFMA_Q(0, 0);                                                         \
  MFMA_Q(0, 1);                                                         \
  LDA(1);                                                               \
  MFMA_Q(1, 0);                                                         \
  MFMA_Q(1, 1);

#define FFN_BOUNDARY(t, NT)                                             \
  __builtin_amdgcn_s_barrier();                                         \
  __builtin_amdgcn_sched_barrier(0);                                    \
  if ((t) + 2 < (NT)) { FFN_STAGE((t)+2, (t)&1); }                      \
  if ((t) + 1 < (NT)){                                                  \
    if ((t) + 2 < (NT)) { asm volatile("s_waitcnt vmcnt(8)" ::: "memory"); } \
    else                { asm volatile("s_waitcnt vmcnt(0)" ::: "memory"); } \
    __builtin_amdgcn_sched_barrier(0);                                  \
    __builtin_amdgcn_s_barrier();                                       \
  }

// ---------------- GEMM 1: H = gelu(Xg @ W1 + b1), K = DIM -------------------
__global__ __launch_bounds__(512, 2) void ffn1_kernel(
    const short* __restrict__ Xb, const short* __restrict__ W1t,
    const float* __restrict__ b1, const int* __restrict__ ctrl,
    const int* __restrict__ rowTok, short* __restrict__ H)
{
  int e, mt, nb;
  xcd_map(NF/256, nb, mt, e);
  int cap = ctrl[24+e];
  if (mt * 256 >= cap) return;
  int rowbase = ctrl[16+e] + mt * 256;

  FFN_DECLS;

  const short* ap[4];
  #pragma unroll
  for (int j = 0; j < 4; j++){
    int g = rowTok[rowbase + w*32 + j*8 + rsub];
    ap[j] = Xb + (size_t)g * DIM + sw;
  }
  const short* bbase = W1t + ((size_t)e * NF + (size_t)nb * 256) * DIM; // [n][k]
  const short* bp[4];
  #pragma unroll
  for (int j = 0; j < 4; j++)
    bp[j] = bbase + (size_t)(w*32 + j*8 + rsub) * DIM + sw;

  FFN_PROLOGUE;

  const int NT = DIM / BKK;   // 16
  short8 aq[4][2], bq[4][2];
  for (int t = 0; t < NT; t++){
    int s = t & 1;
    { FFN_ITER_BODY(s); }
    FFN_BOUNDARY(t, NT);
  }

  // epilogue: +b1, exact gelu, store bf16 H
  #pragma unroll
  for (int ni = 0; ni < 4; ni++){
    int f = nb*256 + wn*64 + ni*16 + ml;
    float bb = b1[e*NF + f];
    #pragma unroll
    for (int mh = 0; mh < 2; mh++){
      #pragma unroll
      for (int mi = 0; mi < 4; mi++){
        #pragma unroll
        for (int r = 0; r < 4; r++){
          int m = wm*128 + mh*64 + mi*16 + q*4 + r;
          float v = acc[mh*4+mi][ni][r] + bb;
          float h = 0.5f * v * (1.f + erff(v * 0.70710678118654752f));
          H[(size_t)(rowbase + m) * NF + f] = f2bf(h);
        }
      }
    }
  }
}

// ---------------- GEMM 2: Yf += H @ W2 (f32 atomic, K split 2-way) ----------
__global__ __launch_bounds__(512, 2) void ffn2_kernel(
    const short* __restrict__ H, const short* __restrict__ W2t,
    const int* __restrict__ ctrl, float* __restrict__ Yf)
{
  int e, mt, xo;
  xcd_map((DIM/256)*KS2, xo, mt, e);
  int nb = xo & 3, kc = xo >> 2;       // kc in [0, KS2)
  int cap = ctrl[24+e];
  if (mt * 256 >= cap) return;
  int rowbase = ctrl[16+e] + mt * 256;

  FFN_DECLS;

  const short* ap[4];
  #pragma unroll
  for (int j = 0; j < 4; j++){
    int r = rowbase + w*32 + j*8 + rsub;
    ap[j] = H + (size_t)r * NF + (size_t)kc * (NF/KS2) + sw;
  }
  const short* bbase = W2t + ((size_t)e * DIM + (size_t)nb * 256) * NF; // [n][k]
  const short* bp[4];
  #pragma unroll
  for (int j = 0; j < 4; j++)
    bp[j] = bbase + (size_t)(w*32 + j*8 + rsub) * NF + (size_t)kc * (NF/KS2) + sw;

  FFN_PROLOGUE;

  const int NT = (NF/KS2) / BKK;   // 32
  short8 aq[4][2], bq[4][2];
  for (int t = 0; t < NT; t++){
    int s = t & 1;
    { FFN_ITER_BODY(s); }
    FFN_BOUNDARY(t, NT);
  }

  // epilogue: f32 atomic accumulate (bias applied in combine)
  #pragma unroll
  for (int ni = 0; ni < 4; ni++){
    int d = nb*256 + wn*64 + ni*16 + ml;
    #pragma unroll
    for (int mh = 0; mh < 2; mh++){
      #pragma unroll
      for (int mi = 0; mi < 4; mi++){
        #pragma unroll
        for (int r = 0; r < 4; r++){
          int m = wm*128 + mh*64 + mi*16 + q*4 + r;
          atomicAdd(&Yf[(size_t)(rowbase + m) * DIM + d], acc[mh*4+mi][ni][r]);
        }
      }
    }
  }
}

// ---------------- combine: out = g0*(y0+b2[e0]) + g1*(y1+b2[e1]) ------------
__global__ __launch_bounds__(256) void combine_kernel(
    const float* __restrict__ Yf, const int* __restrict__ tok2row,
    const int* __restrict__ topi, const float* __restrict__ gatev,
    const float* __restrict__ b2, float* __restrict__ out)
{
  int idx = blockIdx.x * 256 + threadIdx.x;   // over N_TOK * (DIM/8)
  int t = idx >> 7, d8 = idx & 127;
  int r0 = tok2row[t*2], r1 = tok2row[t*2 + 1];
  int e0 = topi[t*2],    e1 = topi[t*2 + 1];
  float g0 = gatev[t*2], g1 = gatev[t*2 + 1];
  const f32x4* y0 = (const f32x4*)(Yf + (size_t)r0 * DIM + d8*8);
  const f32x4* y1 = (const f32x4*)(Yf + (size_t)r1 * DIM + d8*8);
  const f32x4* c0 = (const f32x4*)(b2 + (size_t)e0 * DIM + d8*8);
  const f32x4* c1 = (const f32x4*)(b2 + (size_t)e1 * DIM + d8*8);
  f32x4* dst = (f32x4*)(out + (size_t)t * DIM + d8*8);
  #pragma unroll
  for (int h = 0; h < 2; h++){
    f32x4 o;
    #pragma unroll
    for (int j = 0; j < 4; j++)
      o[j] = g0 * (y0[h][j] + c0[h][j]) + g1 * (y1[h][j] + c1[h][j]);
    dst[h] = o;
  }
}

// ---------------- launch ----------------------------------------------------
extern "C" void kernel_launch(void* const* d_in, const int* in_sizes, int n_in,
                              void* d_out, int out_size, void* d_ws, size_t ws_size,
                              hipStream_t stream)
{
  const float* x  = (const float*)d_in[0];
  const float* gw = (const float*)d_in[1];
  const float* w1 = (const float*)d_in[2];
  const float* b1 = (const float*)d_in[3];
  const float* w2 = (const float*)d_in[4];
  const float* b2 = (const float*)d_in[5];
  float* out = (float*)d_out;

  char* ws = (char*)d_ws;
  size_t o = 0;
  int*   ctrl    = (int*)(ws + o); o += 256;
  int*   topi    = (int*)(ws + o); o += (size_t)N_TOK*2*4;
  float* gatev   = (float*)(ws + o); o += (size_t)N_TOK*2*4;
  int*   rowTok  = (int*)(ws + o); o += (size_t)RCAP*4;
  int*   tok2row = (int*)(ws + o); o += (size_t)N_TOK*2*4;
  o = (o + 255) & ~(size_t)255;
  short* Xb  = (short*)(ws + o); o += (size_t)(N_TOK + 1)*DIM*2;
  short* W1t = (short*)(ws + o); o += (size_t)NE*DIM*NF*2;
  short* W2t = (short*)(ws + o); o += (size_t)NE*NF*DIM*2;
  short* H   = (short*)(ws + o); o += (size_t)RCAP*NF*2;
  float* Yf  = (float*)(ws + o); o += (size_t)RCAP*DIM*4;
  (void)in_sizes; (void)n_in; (void)out_size;

  if (o > ws_size) return;   // clean bail (diagnostic) instead of OOB crash

  hipMemsetAsync(ctrl, 0, 256, stream);
  hipMemsetAsync(Yf, 0, (size_t)RCAP*DIM*4, stream);
  gate_kernel<<<N_TOK/4, 256, 0, stream>>>(x, gw, topi, gatev, ctrl);
  scan_kernel<<<1, 64, 0, stream>>>(ctrl);
  scatter_kernel<<<N_TOK/256, 256, 0, stream>>>(topi, ctrl, rowTok, tok2row);
  pad_kernel<<<NE, 256, 0, stream>>>(ctrl, rowTok);
  cast_x_kernel<<<((N_TOK + 1)*DIM/8 + 255)/256, 256, 0, stream>>>(x, Xb);
  transpose_cast_kernel<<<dim3(NF/64, DIM/64, NE), 256, 0, stream>>>(w1, W1t, DIM, NF);
  transpose_cast_kernel<<<dim3(DIM/64, NF/64, NE), 256, 0, stream>>>(w2, W2t, NF, DIM);
  ffn1_kernel<<<dim3(NF/256, MAXMT, NE), 512, 0, stream>>>(Xb, W1t, b1, ctrl, rowTok, H);
  ffn2_kernel<<<dim3((DIM/256)*KS2, MAXMT, NE), 512, 0, stream>>>(H, W2t, ctrl, Yf);
  combine_kernel<<<N_TOK*(DIM/8)/256, 256, 0, stream>>>(Yf, tok2row, topi, gatev, b2, out);
}

// Round 3
// 1119.358 us; speedup vs baseline: 1.1069x; 1.1069x over previous
//
#include <hip/hip_runtime.h>
#include <stdint.h>
#include <stddef.h>

#define N_TOK 8192
#define DIM   1024
#define NE    8
#define NF    4096
#define TM    256                 /* M-pad granularity (matches BM) */
#define BKK   64
#define RCAP  (N_TOK*2 + NE*TM)   /* 18432 padded assignment rows */
#define MAXMT (N_TOK/TM)          /* 32 worst-case m-tiles per expert */
#define KS2   2                   /* ffn2 K-split (dual bf16 partials) */

typedef __attribute__((ext_vector_type(8))) short short8;
typedef __attribute__((ext_vector_type(4))) float f32x4;

__device__ __forceinline__ float bf2f(short s){
  unsigned u = ((unsigned)(unsigned short)s) << 16;
  return __builtin_bit_cast(float, u);
}
__device__ __forceinline__ short f2bf(float f){
  unsigned u = __builtin_bit_cast(unsigned, f);
  u += 0x7fffu + ((u >> 16) & 1u);   // RNE (inputs are tame, no NaN)
  return (short)(u >> 16);
}

#define GLD_LDS16(g, l) __builtin_amdgcn_global_load_lds( \
    (const __attribute__((address_space(1))) void*)(g),   \
    (__attribute__((address_space(3))) void*)(l), 16, 0, 0)

// bijective XCD-chunk swizzle (nwg % 8 == 0 for both ffn grids)
__device__ __forceinline__ void xcd_map(int nx, int& xo, int& mt, int& e){
  int h   = blockIdx.x + nx * (blockIdx.y + MAXMT * blockIdx.z);
  int nwg = nx * MAXMT * NE;
  int q   = nwg >> 3;
  int wk  = (h & 7) * q + (h >> 3);
  xo = wk % nx;
  int r = wk / nx;
  mt = r % MAXMT;
  e  = r / MAXMT;
}

// ---------------- gating (pure fp32: selection must match reference) --------
__global__ __launch_bounds__(256) void gate_kernel(
    const float* __restrict__ x, const float* __restrict__ gw,
    int* __restrict__ topi, float* __restrict__ gatev, int* __restrict__ ctrl)
{
  int t = blockIdx.x * 4 + (threadIdx.x >> 6);
  int lane = threadIdx.x & 63;
  const float* xr = x + (size_t)t * DIM;
  float p[NE];
  #pragma unroll
  for (int e = 0; e < NE; e++) p[e] = 0.f;
  for (int i = lane; i < DIM; i += 64){
    float xv = xr[i];
    const float* g = gw + i * NE;
    #pragma unroll
    for (int e = 0; e < NE; e++) p[e] += xv * g[e];
  }
  #pragma unroll
  for (int off = 32; off > 0; off >>= 1){
    #pragma unroll
    for (int e = 0; e < NE; e++) p[e] += __shfl_xor(p[e], off, 64);
  }
  if (lane == 0){
    int i1 = 0; float v1 = p[0];
    #pragma unroll
    for (int e = 1; e < NE; e++) if (p[e] > v1){ v1 = p[e]; i1 = e; }
    int i2 = -1; float v2 = -3.4e38f;
    #pragma unroll
    for (int e = 0; e < NE; e++) if (e != i1 && p[e] > v2){ v2 = p[e]; i2 = e; }
    float ex = expf(v2 - v1);          // v1 >= v2
    float g2 = ex / (1.f + ex);
    float g1 = 1.f - g2;
    topi[t*2]   = i1;  topi[t*2+1]  = i2;
    gatev[t*2]  = g1;  gatev[t*2+1] = g2;
    atomicAdd(&ctrl[i1], 1);
    atomicAdd(&ctrl[i2], 1);
  }
}

// ctrl ints: [0..7]=counts  [8..15]=cursors  [16..23]=offs  [24..31]=caps
__global__ void scan_kernel(int* ctrl){
  if (threadIdx.x == 0){
    int tot = 0;
    for (int e = 0; e < NE; e++){
      int c = ctrl[e];
      int cap = (c + TM - 1) & ~(TM - 1);
      ctrl[16+e] = tot; ctrl[24+e] = cap; tot += cap;
    }
  }
}

__global__ __launch_bounds__(256) void scatter_kernel(
    const int* __restrict__ topi, int* ctrl,
    int* __restrict__ rowTok, int* __restrict__ tok2row)
{
  int t = blockIdx.x * 256 + threadIdx.x;
  #pragma unroll
  for (int k = 0; k < 2; k++){
    int e = topi[t*2 + k];
    int pos = atomicAdd(&ctrl[8+e], 1);
    int r = ctrl[16+e] + pos;
    rowTok[r] = t;
    tok2row[t*2 + k] = r;
  }
}

__global__ void pad_kernel(const int* __restrict__ ctrl, int* __restrict__ rowTok){
  int e = blockIdx.x;
  int cnt = ctrl[e], cap = ctrl[24+e], off = ctrl[16+e];
  for (int i = cnt + threadIdx.x; i < cap; i += blockDim.x)
    rowTok[off + i] = N_TOK;    // sentinel -> zero row of Xb
}

// ---------------- casts -----------------------------------------------------
__global__ __launch_bounds__(256) void cast_x_kernel(
    const float* __restrict__ x, short* __restrict__ xb)
{
  size_t i = ((size_t)blockIdx.x * 256 + threadIdx.x) * 8;
  if (i >= (size_t)(N_TOK + 1) * DIM) return;
  short8 o;
  if (i < (size_t)N_TOK * DIM){
    #pragma unroll
    for (int j = 0; j < 8; j++) o[j] = f2bf(x[i + j]);
  } else {
    #pragma unroll
    for (int j = 0; j < 8; j++) o[j] = 0;
  }
  *(short8*)(xb + i) = o;
}

// src[e][k][n] fp32 -> dst[e][n][k] bf16, LDS-tiled 64x64 transpose.
__global__ __launch_bounds__(256) void transpose_cast_kernel(
    const float* __restrict__ src, short* __restrict__ dst, int Kd, int Nd)
{
  __shared__ float Ls[64][65];
  int e = blockIdx.z;
  int k0 = blockIdx.y * 64, n0 = blockIdx.x * 64;
  const float* s = src + (size_t)e * Kd * Nd;
  short*       d = dst + (size_t)e * Kd * Nd;
  int t = threadIdx.x;
  int kr = t >> 4, nc = (t & 15) * 4;
  #pragma unroll
  for (int rr = 0; rr < 4; rr++){
    int k = rr*16 + kr;
    f32x4 v = *(const f32x4*)(s + (size_t)(k0 + k) * Nd + n0 + nc);
    Ls[k][nc+0] = v[0]; Ls[k][nc+1] = v[1];
    Ls[k][nc+2] = v[2]; Ls[k][nc+3] = v[3];
  }
  __syncthreads();
  int nr = t >> 2, kc = (t & 3) * 16;
  short o[16];
  #pragma unroll
  for (int i = 0; i < 16; i++) o[i] = f2bf(Ls[kc + i][nr]);
  short* dp = d + (size_t)(n0 + nr) * Kd + k0 + kc;
  *(short8*)(dp)     = *(short8*)&o[0];
  *(short8*)(dp + 8) = *(short8*)&o[8];
}

// ============ grouped GEMM, 256x256 tile, 8 waves, 4 quadrant phases ========
// LDS XOR swizzle: physical 16B chunk p of row r holds logical chunk p^(r&7)
// (source address pre-swizzled; global_load_lds dest stays linear).
// Per K-tile: reads spread 12/4/8 over phases; stage of tile t+2 split into
// A-half (phase 3) and B-half (phase 4), safe because all slot reads are
// drained via lgkmcnt(0)+barrier first; vmcnt(8) once per tile (tile t+1
// landed), never 0 mid-loop.  K-loop is NOT unrolled (I-cache discipline).

#define FFN_DECLS                                                       \
  __shared__ __align__(16) short As[2][256][BKK];                       \
  __shared__ __align__(16) short Bs[2][256][BKK];                       \
  int tid = threadIdx.x, w = tid >> 6, lane = tid & 63;                 \
  int rsub = lane >> 3, ksub = lane & 7;                                \
  int sw = (ksub ^ rsub) * 8;                                           \
  char* const AsB = (char*)As; char* const BsB = (char*)Bs;             \
  int ml = lane & 15, q = lane >> 4;                                    \
  int wm = w >> 2, wn = w & 3;                                          \
  int mx = ml & 7;                                                      \
  f32x4 acc[8][4];                                                      \
  _Pragma("unroll")                                                     \
  for (int i = 0; i < 8; i++){                                          \
    _Pragma("unroll")                                                   \
    for (int j = 0; j < 4; j++){ f32x4 z = {0.f,0.f,0.f,0.f}; acc[i][j] = z; } \
  }

#define MFMA_Q2(A_, mh, B_, nh)                                         \
  __builtin_amdgcn_s_setprio(1);                                        \
  _Pragma("unroll")                                                     \
  for (int mi = 0; mi < 4; mi++){                                       \
    _Pragma("unroll")                                                   \
    for (int ni = 0; ni < 2; ni++){                                     \
      _Pragma("unroll")                                                 \
      for (int ks = 0; ks < 2; ks++)                                    \
        acc[(mh)*4+mi][(nh)*2+ni] = __builtin_amdgcn_mfma_f32_16x16x32_bf16( \
            A_[mi][ks], B_[(nh)*2+ni][ks], acc[(mh)*4+mi][(nh)*2+ni], 0, 0, 0); \
    }                                                                   \
  }                                                                     \
  __builtin_amdgcn_s_setprio(0);

// one K-tile; DO_STAGE/DO_W8/DO_W0 are 0/1 literals (dead code folds away)
#define FFN_TILE(s, DO_STAGE, DO_W8, DO_W0)                             \
  {                                                                     \
    const short8* Ar = (const short8*)(AsB + (s)*32768);                \
    const short8* Br = (const short8*)(BsB + (s)*32768);                \
    short8 a[4][2], b[4][2];                                            \
    /* P1: read a-low + b01 */                                          \
    _Pragma("unroll") for (int mi = 0; mi < 4; mi++)                    \
      _Pragma("unroll") for (int ks = 0; ks < 2; ks++)                  \
        a[mi][ks] = Ar[(wm*128 + mi*16 + ml)*8 + ((ks*4+q)^mx)];        \
    _Pragma("unroll") for (int ni = 0; ni < 2; ni++)                    \
      _Pragma("unroll") for (int ks = 0; ks < 2; ks++)                  \
        b[ni][ks] = Br[(wn*64 + ni*16 + ml)*8 + ((ks*4+q)^mx)];         \
    __builtin_amdgcn_s_barrier();                                       \
    MFMA_Q2(a, 0, b, 0);                                                \
    __builtin_amdgcn_s_barrier();                                       \
    /* P2: read b23, compute Q01 (a-low x b23) */                       \
    _Pragma("unroll") for (int ni = 2; ni < 4; ni++)                    \
      _Pragma("unroll") for (int ks = 0; ks < 2; ks++)                  \
        b[ni][ks] = Br[(wn*64 + ni*16 + ml)*8 + ((ks*4+q)^mx)];         \
    MFMA_Q2(a, 0, b, 1);                                                \
    __builtin_amdgcn_s_barrier();                                       \
    /* P3: read a-high (a-low dead, regs reuse); drain + fence, then */ \
    /* it is safe for ANY wave to overwrite slot s via DMA           */ \
    _Pragma("unroll") for (int mi = 0; mi < 4; mi++)                    \
      _Pragma("unroll") for (int ks = 0; ks < 2; ks++)                  \
        a[mi][ks] = Ar[(wm*128 + 64 + mi*16 + ml)*8 + ((ks*4+q)^mx)];   \
    asm volatile("s_waitcnt lgkmcnt(0)" ::: "memory");                  \
    __builtin_amdgcn_sched_barrier(0);                                  \
    __builtin_amdgcn_s_barrier();                                       \
    if (DO_STAGE){                                                      \
      _Pragma("unroll")                                                 \
      for (int j = 0; j < 4; j++) GLD_LDS16(apg[j], AsB + (s)*32768 + (w*4+j)*1024); \
    }                                                                   \
    MFMA_Q2(a, 1, b, 0);                                                \
    __builtin_amdgcn_s_barrier();                                       \
    if (DO_STAGE){                                                      \
      _Pragma("unroll")                                                 \
      for (int j = 0; j < 4; j++) GLD_LDS16(bpg[j], BsB + (s)*32768 + (w*4+j)*1024); \
      _Pragma("unroll")                                                 \
      for (int j = 0; j < 4; j++){ apg[j] += BKK; bpg[j] += BKK; }      \
    }                                                                   \
    MFMA_Q2(a, 1, b, 1);                                                \
    if (DO_W8){ asm volatile("s_waitcnt vmcnt(8)" ::: "memory");        \
                __builtin_amdgcn_sched_barrier(0); }                    \
    if (DO_W0){ asm volatile("s_waitcnt vmcnt(0)" ::: "memory");        \
                __builtin_amdgcn_sched_barrier(0); }                    \
    __builtin_amdgcn_s_barrier();                                       \
  }

#define FFN_PROLOGUE                                                    \
  _Pragma("unroll")                                                     \
  for (int j = 0; j < 4; j++) GLD_LDS16(ap[j],       AsB + (w*4+j)*1024);          \
  _Pragma("unroll")                                                     \
  for (int j = 0; j < 4; j++) GLD_LDS16(bp[j],       BsB + (w*4+j)*1024);          \
  _Pragma("unroll")                                                     \
  for (int j = 0; j < 4; j++) GLD_LDS16(ap[j] + BKK, AsB + 32768 + (w*4+j)*1024);  \
  _Pragma("unroll")                                                     \
  for (int j = 0; j < 4; j++) GLD_LDS16(bp[j] + BKK, BsB + 32768 + (w*4+j)*1024);  \
  asm volatile("s_waitcnt vmcnt(8)" ::: "memory");                      \
  __builtin_amdgcn_sched_barrier(0);                                    \
  __builtin_amdgcn_s_barrier();                                         \
  const short* apg[4]; const short* bpg[4];                             \
  _Pragma("unroll")                                                     \
  for (int j = 0; j < 4; j++){ apg[j] = ap[j] + 2*BKK; bpg[j] = bp[j] + 2*BKK; }

#define FFN_MAIN(NT)                                                    \
  FFN_PROLOGUE;                                                         \
  _Pragma("unroll 1")                                                   \
  for (int t = 0; t < (NT) - 2; t++){                                   \
    int s_ = t & 1;                                                     \
    FFN_TILE(s_, 1, 1, 0);                                              \
  }                                                                     \
  FFN_TILE(((NT)-2) & 1, 0, 0, 1);                                      \
  FFN_TILE(((NT)-1) & 1, 0, 0, 0);

// ---------------- GEMM 1: H = gelu(Xg @ W1 + b1), K = DIM -------------------
__global__ __launch_bounds__(512, 2) void ffn1_kernel(
    const short* __restrict__ Xb, const short* __restrict__ W1t,
    const float* __restrict__ b1, const int* __restrict__ ctrl,
    const int* __restrict__ rowTok, short* __restrict__ H)
{
  int e, mt, nb;
  xcd_map(NF/256, nb, mt, e);
  int cap = ctrl[24+e];
  if (mt * 256 >= cap) return;
  int rowbase = ctrl[16+e] + mt * 256;

  FFN_DECLS;

  const short* ap[4];
  #pragma unroll
  for (int j = 0; j < 4; j++){
    int g = rowTok[rowbase + w*32 + j*8 + rsub];
    ap[j] = Xb + (size_t)g * DIM + sw;
  }
  const short* bbase = W1t + ((size_t)e * NF + (size_t)nb * 256) * DIM; // [n][k]
  const short* bp[4];
  #pragma unroll
  for (int j = 0; j < 4; j++)
    bp[j] = bbase + (size_t)(w*32 + j*8 + rsub) * DIM + sw;

  FFN_MAIN(DIM/BKK);   // 16 K-tiles

  // epilogue: +b1, exact gelu, store bf16 H
  #pragma unroll
  for (int ni = 0; ni < 4; ni++){
    int f = nb*256 + wn*64 + ni*16 + ml;
    float bb = b1[e*NF + f];
    #pragma unroll
    for (int mh = 0; mh < 2; mh++){
      #pragma unroll
      for (int mi = 0; mi < 4; mi++){
        #pragma unroll
        for (int r = 0; r < 4; r++){
          int m = wm*128 + mh*64 + mi*16 + q*4 + r;
          float v = acc[mh*4+mi][ni][r] + bb;
          float h = 0.5f * v * (1.f + erff(v * 0.70710678118654752f));
          H[(size_t)(rowbase + m) * NF + f] = f2bf(h);
        }
      }
    }
  }
}

// ------- GEMM 2: Yp[kc] = H(:, kc-half) @ W2(kc-half) (bias in combine) -----
__global__ __launch_bounds__(512, 2) void ffn2_kernel(
    const short* __restrict__ H, const short* __restrict__ W2t,
    const int* __restrict__ ctrl, short* __restrict__ Yp)
{
  int e, mt, xo;
  xcd_map((DIM/256)*KS2, xo, mt, e);
  int nb = xo & 3, kc = xo >> 2;       // kc in [0, KS2)
  int cap = ctrl[24+e];
  if (mt * 256 >= cap) return;
  int rowbase = ctrl[16+e] + mt * 256;

  FFN_DECLS;

  const short* ap[4];
  #pragma unroll
  for (int j = 0; j < 4; j++){
    int r = rowbase + w*32 + j*8 + rsub;
    ap[j] = H + (size_t)r * NF + (size_t)kc * (NF/KS2) + sw;
  }
  const short* bbase = W2t + ((size_t)e * DIM + (size_t)nb * 256) * NF; // [n][k]
  const short* bp[4];
  #pragma unroll
  for (int j = 0; j < 4; j++)
    bp[j] = bbase + (size_t)(w*32 + j*8 + rsub) * NF + (size_t)kc * (NF/KS2) + sw;

  FFN_MAIN((NF/KS2)/BKK);   // 32 K-tiles

  // epilogue: bf16 partial store (no bias here)
  short* Yk = Yp + (size_t)kc * RCAP * DIM;
  #pragma unroll
  for (int ni = 0; ni < 4; ni++){
    int d = nb*256 + wn*64 + ni*16 + ml;
    #pragma unroll
    for (int mh = 0; mh < 2; mh++){
      #pragma unroll
      for (int mi = 0; mi < 4; mi++){
        #pragma unroll
        for (int r = 0; r < 4; r++){
          int m = wm*128 + mh*64 + mi*16 + q*4 + r;
          Yk[(size_t)(rowbase + m) * DIM + d] = f2bf(acc[mh*4+mi][ni][r]);
        }
      }
    }
  }
}

// -------- combine: out = g0*(y0a+y0b+b2[e0]) + g1*(y1a+y1b+b2[e1]) ----------
__global__ __launch_bounds__(256) void combine_kernel(
    const short* __restrict__ Yp, const int* __restrict__ tok2row,
    const int* __restrict__ topi, const float* __restrict__ gatev,
    const float* __restrict__ b2, float* __restrict__ out)
{
  int idx = blockIdx.x * 256 + threadIdx.x;   // over N_TOK * (DIM/8)
  int t = idx >> 7, d8 = idx & 127;
  int r0 = tok2row[t*2], r1 = tok2row[t*2 + 1];
  int e0 = topi[t*2],    e1 = topi[t*2 + 1];
  float g0 = gatev[t*2], g1 = gatev[t*2 + 1];
  const size_t half = (size_t)RCAP * DIM;
  short8 y0a = *(const short8*)(Yp + (size_t)r0 * DIM + d8*8);
  short8 y0b = *(const short8*)(Yp + half + (size_t)r0 * DIM + d8*8);
  short8 y1a = *(const short8*)(Yp + (size_t)r1 * DIM + d8*8);
  short8 y1b = *(const short8*)(Yp + half + (size_t)r1 * DIM + d8*8);
  const float* c0 = b2 + (size_t)e0 * DIM + d8*8;
  const float* c1 = b2 + (size_t)e1 * DIM + d8*8;
  float o[8];
  #pragma unroll
  for (int j = 0; j < 8; j++)
    o[j] = g0 * (bf2f(y0a[j]) + bf2f(y0b[j]) + c0[j])
         + g1 * (bf2f(y1a[j]) + bf2f(y1b[j]) + c1[j]);
  f32x4 v0 = {o[0], o[1], o[2], o[3]};
  f32x4 v1 = {o[4], o[5], o[6], o[7]};
  f32x4* dst = (f32x4*)(out + (size_t)t * DIM + d8*8);
  dst[0] = v0; dst[1] = v1;
}

// ---------------- launch ----------------------------------------------------
extern "C" void kernel_launch(void* const* d_in, const int* in_sizes, int n_in,
                              void* d_out, int out_size, void* d_ws, size_t ws_size,
                              hipStream_t stream)
{
  const float* x  = (const float*)d_in[0];
  const float* gw = (const float*)d_in[1];
  const float* w1 = (const float*)d_in[2];
  const float* b1 = (const float*)d_in[3];
  const float* w2 = (const float*)d_in[4];
  const float* b2 = (const float*)d_in[5];
  float* out = (float*)d_out;

  char* ws = (char*)d_ws;
  size_t o = 0;
  int*   ctrl    = (int*)(ws + o); o += 256;
  int*   topi    = (int*)(ws + o); o += (size_t)N_TOK*2*4;
  float* gatev   = (float*)(ws + o); o += (size_t)N_TOK*2*4;
  int*   rowTok  = (int*)(ws + o); o += (size_t)RCAP*4;
  int*   tok2row = (int*)(ws + o); o += (size_t)N_TOK*2*4;
  o = (o + 255) & ~(size_t)255;
  short* Xb  = (short*)(ws + o); o += (size_t)(N_TOK + 1)*DIM*2;
  short* W1t = (short*)(ws + o); o += (size_t)NE*DIM*NF*2;
  short* W2t = (short*)(ws + o); o += (size_t)NE*NF*DIM*2;
  short* H   = (short*)(ws + o); o += (size_t)RCAP*NF*2;
  short* Yp  = (short*)(ws + o); o += (size_t)KS2*RCAP*DIM*2;
  (void)in_sizes; (void)n_in; (void)out_size;

  if (o > ws_size) return;   // clean bail (diagnostic) instead of OOB crash

  hipMemsetAsync(ctrl, 0, 256, stream);
  gate_kernel<<<N_TOK/4, 256, 0, stream>>>(x, gw, topi, gatev, ctrl);
  scan_kernel<<<1, 64, 0, stream>>>(ctrl);
  scatter_kernel<<<N_TOK/256, 256, 0, stream>>>(topi, ctrl, rowTok, tok2row);
  pad_kernel<<<NE, 256, 0, stream>>>(ctrl, rowTok);
  cast_x_kernel<<<((N_TOK + 1)*DIM/8 + 255)/256, 256, 0, stream>>>(x, Xb);
  transpose_cast_kernel<<<dim3(NF/64, DIM/64, NE), 256, 0, stream>>>(w1, W1t, DIM, NF);
  transpose_cast_kernel<<<dim3(DIM/64, NF/64, NE), 256, 0, stream>>>(w2, W2t, NF, DIM);
  ffn1_kernel<<<dim3(NF/256, MAXMT, NE), 512, 0, stream>>>(Xb, W1t, b1, ctrl, rowTok, H);
  ffn2_kernel<<<dim3((DIM/256)*KS2, MAXMT, NE), 512, 0, stream>>>(H, W2t, ctrl, Yp);
  combine_kernel<<<N_TOK*(DIM/8)/256, 256, 0, stream>>>(Yp, tok2row, topi, gatev, b2, out);
}

// Round 4
// 1116.704 us; speedup vs baseline: 1.1095x; 1.0024x over previous
//
#include <hip/hip_runtime.h>
#include <stdint.h>
#include <stddef.h>

#define N_TOK 8192
#define DIM   1024
#define NE    8
#define NF    4096
#define TM    128
#define TN    128
#define BKK   64
#define RCAP  (N_TOK*2 + NE*TM)   /* 17408 padded assignment rows */
#define MTL   (N_TOK*2/TM + NE - 1) /* 135: worst-case total m-tiles (tight!) */

typedef __attribute__((ext_vector_type(8))) short short8;
typedef __attribute__((ext_vector_type(4))) float f32x4;

__device__ __forceinline__ float bf2f(short s){
  unsigned u = ((unsigned)(unsigned short)s) << 16;
  return __builtin_bit_cast(float, u);
}
__device__ __forceinline__ short f2bf(float f){
  unsigned u = __builtin_bit_cast(unsigned, f);
  u += 0x7fffu + ((u >> 16) & 1u);   // RNE (inputs are tame, no NaN)
  return (short)(u >> 16);
}

#define GLD_LDS16(g, l) __builtin_amdgcn_global_load_lds( \
    (const __attribute__((address_space(1))) void*)(g),   \
    (__attribute__((address_space(3))) void*)(l), 16, 0, 0)

// bijective XCD-chunk map over a compact (nx x MTL) grid; nwg % 8 == 0.
__device__ __forceinline__ void xcd_map2(int nx, int& nb, int& tt){
  int h   = blockIdx.x + nx * blockIdx.y;
  int nwg = nx * MTL;
  int q   = nwg >> 3;
  int wk  = (h & 7) * q + (h >> 3);
  nb = wk % nx;
  tt = wk / nx;
}

// ---------------- gating (pure fp32: selection must match reference) --------
__global__ __launch_bounds__(256) void gate_kernel(
    const float* __restrict__ x, const float* __restrict__ gw,
    int* __restrict__ topi, float* __restrict__ gatev, int* __restrict__ ctrl)
{
  int t = blockIdx.x * 4 + (threadIdx.x >> 6);
  int lane = threadIdx.x & 63;
  const float* xr = x + (size_t)t * DIM;
  float p[NE];
  #pragma unroll
  for (int e = 0; e < NE; e++) p[e] = 0.f;
  for (int i = lane; i < DIM; i += 64){
    float xv = xr[i];
    const float* g = gw + i * NE;
    #pragma unroll
    for (int e = 0; e < NE; e++) p[e] += xv * g[e];
  }
  #pragma unroll
  for (int off = 32; off > 0; off >>= 1){
    #pragma unroll
    for (int e = 0; e < NE; e++) p[e] += __shfl_xor(p[e], off, 64);
  }
  if (lane == 0){
    int i1 = 0; float v1 = p[0];
    #pragma unroll
    for (int e = 1; e < NE; e++) if (p[e] > v1){ v1 = p[e]; i1 = e; }
    int i2 = -1; float v2 = -3.4e38f;
    #pragma unroll
    for (int e = 0; e < NE; e++) if (e != i1 && p[e] > v2){ v2 = p[e]; i2 = e; }
    float ex = expf(v2 - v1);          // v1 >= v2
    float g2 = ex / (1.f + ex);
    float g1 = 1.f - g2;
    topi[t*2]   = i1;  topi[t*2+1]  = i2;
    gatev[t*2]  = g1;  gatev[t*2+1] = g2;
    atomicAdd(&ctrl[i1], 1);
    atomicAdd(&ctrl[i2], 1);
  }
}

// ctrl ints: [0..7]=counts [8..15]=cursors [16..23]=offs [24..31]=caps [32]=ntiles
// Also builds the compact tile worklist: (expert, rowbase) per m-tile.
__global__ void scan_kernel(int* ctrl, int* __restrict__ tileE, int* __restrict__ tileR){
  if (threadIdx.x == 0){
    int tot = 0, nt = 0;
    for (int e = 0; e < NE; e++){
      int c = ctrl[e];
      int cap = (c + TM - 1) & ~(TM - 1);
      ctrl[16+e] = tot; ctrl[24+e] = cap;
      for (int m = 0; m < cap; m += TM){
        tileE[nt] = e; tileR[nt] = tot + m; nt++;
      }
      tot += cap;
    }
    ctrl[32] = nt;   // nt <= MTL always (sum of counts is fixed = 2*N_TOK)
  }
}

__global__ __launch_bounds__(256) void scatter_kernel(
    const int* __restrict__ topi, int* ctrl,
    int* __restrict__ rowTok, int* __restrict__ tok2row)
{
  int t = blockIdx.x * 256 + threadIdx.x;
  #pragma unroll
  for (int k = 0; k < 2; k++){
    int e = topi[t*2 + k];
    int pos = atomicAdd(&ctrl[8+e], 1);
    int r = ctrl[16+e] + pos;
    rowTok[r] = t;
    tok2row[t*2 + k] = r;
  }
}

__global__ void pad_kernel(const int* __restrict__ ctrl, int* __restrict__ rowTok){
  int e = blockIdx.x;
  int cnt = ctrl[e], cap = ctrl[24+e], off = ctrl[16+e];
  for (int i = cnt + threadIdx.x; i < cap; i += blockDim.x)
    rowTok[off + i] = N_TOK;    // sentinel -> zero row of Xb
}

// ---------------- casts -----------------------------------------------------
__global__ __launch_bounds__(256) void cast_x_kernel(
    const float* __restrict__ x, short* __restrict__ xb)
{
  size_t i = ((size_t)blockIdx.x * 256 + threadIdx.x) * 8;
  if (i >= (size_t)(N_TOK + 1) * DIM) return;
  short8 o;
  if (i < (size_t)N_TOK * DIM){
    #pragma unroll
    for (int j = 0; j < 8; j++) o[j] = f2bf(x[i + j]);
  } else {
    #pragma unroll
    for (int j = 0; j < 8; j++) o[j] = 0;
  }
  *(short8*)(xb + i) = o;
}

// src[e][k][n] fp32 -> dst[e][n][k] bf16, LDS-tiled 64x64 transpose.
__global__ __launch_bounds__(256) void transpose_cast_kernel(
    const float* __restrict__ src, short* __restrict__ dst, int Kd, int Nd)
{
  __shared__ float Ls[64][65];
  int e = blockIdx.z;
  int k0 = blockIdx.y * 64, n0 = blockIdx.x * 64;
  const float* s = src + (size_t)e * Kd * Nd;
  short*       d = dst + (size_t)e * Kd * Nd;
  int t = threadIdx.x;
  int kr = t >> 4, nc = (t & 15) * 4;
  #pragma unroll
  for (int rr = 0; rr < 4; rr++){
    int k = rr*16 + kr;
    f32x4 v = *(const f32x4*)(s + (size_t)(k0 + k) * Nd + n0 + nc);
    Ls[k][nc+0] = v[0]; Ls[k][nc+1] = v[1];
    Ls[k][nc+2] = v[2]; Ls[k][nc+3] = v[3];
  }
  __syncthreads();
  int nr = t >> 2, kc = (t & 3) * 16;
  short o[16];
  #pragma unroll
  for (int i = 0; i < 16; i++) o[i] = f2bf(Ls[kc + i][nr]);
  short* dp = d + (size_t)(n0 + nr) * Kd + k0 + kc;
  *(short8*)(dp)     = *(short8*)&o[0];
  *(short8*)(dp + 8) = *(short8*)&o[8];
}

// ---------------- grouped GEMM 1: H = gelu(Xg @ W1 + b1) --------------------
// R0-proven 128x128 single-buffered loop; compact tile worklist (no ghosts).
// LDS XOR swizzle: physical 16B chunk p of row r holds logical chunk p^(r&7).
__global__ __launch_bounds__(256) void ffn1_kernel(
    const short* __restrict__ Xb, const short* __restrict__ W1t,
    const float* __restrict__ b1, const int* __restrict__ ctrl,
    const int* __restrict__ tileE, const int* __restrict__ tileR,
    const int* __restrict__ rowTok, short* __restrict__ H)
{
  int nb, tt;
  xcd_map2(NF/TN, nb, tt);
  if (tt >= ctrl[32]) return;
  int e = tileE[tt];
  int rowbase = tileR[tt];

  __shared__ __align__(16) short As[TM][BKK];
  __shared__ __align__(16) short Bs[TN][BKK];

  int tid = threadIdx.x, w = tid >> 6, lane = tid & 63;
  int rsub = lane >> 3, ksub = lane & 7;
  int sw = (ksub ^ rsub) * 8;              // swizzled source chunk (shorts)

  const short* ap[4];
  #pragma unroll
  for (int j = 0; j < 4; j++){
    int g = rowTok[rowbase + w*32 + j*8 + rsub];
    ap[j] = Xb + (size_t)g * DIM + sw;
  }
  const short* bbase = W1t + ((size_t)e * NF + (size_t)nb * TN) * DIM;  // [n][k]
  const short* bp[4];
  #pragma unroll
  for (int j = 0; j < 4; j++)
    bp[j] = bbase + (size_t)((w*4 + j)*8 + rsub) * DIM + sw;

  char* AsB = (char*)As; char* BsB = (char*)Bs;
  int ml = lane & 15, q = lane >> 4;
  int wm = w & 1, wn = w >> 1;
  int mx = ml & 7;                         // row&7 for fragment rows
  const short8* Ar = (const short8*)As;
  const short8* Br = (const short8*)Bs;

  f32x4 acc[4][4];
  #pragma unroll
  for (int i = 0; i < 4; i++){
    #pragma unroll
    for (int j = 0; j < 4; j++){ f32x4 z = {0.f,0.f,0.f,0.f}; acc[i][j] = z; }
  }

  for (int kb = 0; kb < DIM/BKK; kb++){
    #pragma unroll
    for (int j = 0; j < 4; j++) GLD_LDS16(ap[j] + kb*BKK, AsB + (w*4 + j)*1024);
    #pragma unroll
    for (int j = 0; j < 4; j++) GLD_LDS16(bp[j] + kb*BKK, BsB + (w*4 + j)*1024);
    __syncthreads();
    #pragma unroll
    for (int ks = 0; ks < 2; ks++){
      int c = (ks*4 + q) ^ mx;             // swizzled chunk for this lane
      short8 a[4], b[4];
      #pragma unroll
      for (int mi = 0; mi < 4; mi++) a[mi] = Ar[(wm*64 + mi*16 + ml)*8 + c];
      #pragma unroll
      for (int ni = 0; ni < 4; ni++) b[ni] = Br[(wn*64 + ni*16 + ml)*8 + c];
      #pragma unroll
      for (int mi = 0; mi < 4; mi++){
        #pragma unroll
        for (int ni = 0; ni < 4; ni++)
          acc[mi][ni] = __builtin_amdgcn_mfma_f32_16x16x32_bf16(a[mi], b[ni], acc[mi][ni], 0, 0, 0);
      }
    }
    __syncthreads();
  }

  // epilogue: +b1, exact gelu, store bf16 H
  #pragma unroll
  for (int ni = 0; ni < 4; ni++){
    int f = nb*TN + wn*64 + ni*16 + ml;
    float bb = b1[e*NF + f];
    #pragma unroll
    for (int mi = 0; mi < 4; mi++){
      #pragma unroll
      for (int r = 0; r < 4; r++){
        int m = wm*64 + mi*16 + q*4 + r;
        float v = acc[mi][ni][r] + bb;
        float h = 0.5f * v * (1.f + erff(v * 0.70710678118654752f));
        H[(size_t)(rowbase + m) * NF + f] = f2bf(h);
      }
    }
  }
}

// ---------------- grouped GEMM 2: Yp = H @ W2 + b2 --------------------------
__global__ __launch_bounds__(256) void ffn2_kernel(
    const short* __restrict__ H, const short* __restrict__ W2t,
    const float* __restrict__ b2, const int* __restrict__ ctrl,
    const int* __restrict__ tileE, const int* __restrict__ tileR,
    short* __restrict__ Yp)
{
  int nb, tt;
  xcd_map2(DIM/TN, nb, tt);
  if (tt >= ctrl[32]) return;
  int e = tileE[tt];
  int rowbase = tileR[tt];

  __shared__ __align__(16) short As[TM][BKK];
  __shared__ __align__(16) short Bs[TN][BKK];

  int tid = threadIdx.x, w = tid >> 6, lane = tid & 63;
  int rsub = lane >> 3, ksub = lane & 7;
  int sw = (ksub ^ rsub) * 8;

  const short* ap[4];
  #pragma unroll
  for (int j = 0; j < 4; j++){
    int r = rowbase + w*32 + j*8 + rsub;
    ap[j] = H + (size_t)r * NF + sw;
  }
  const short* bbase = W2t + ((size_t)e * DIM + (size_t)nb * TN) * NF;  // [n][k]
  const short* bp[4];
  #pragma unroll
  for (int j = 0; j < 4; j++)
    bp[j] = bbase + (size_t)((w*4 + j)*8 + rsub) * NF + sw;

  char* AsB = (char*)As; char* BsB = (char*)Bs;
  int ml = lane & 15, q = lane >> 4;
  int wm = w & 1, wn = w >> 1;
  int mx = ml & 7;
  const short8* Ar = (const short8*)As;
  const short8* Br = (const short8*)Bs;

  f32x4 acc[4][4];
  #pragma unroll
  for (int i = 0; i < 4; i++){
    #pragma unroll
    for (int j = 0; j < 4; j++){ f32x4 z = {0.f,0.f,0.f,0.f}; acc[i][j] = z; }
  }

  for (int kb = 0; kb < NF/BKK; kb++){
    #pragma unroll
    for (int j = 0; j < 4; j++) GLD_LDS16(ap[j] + kb*BKK, AsB + (w*4 + j)*1024);
    #pragma unroll
    for (int j = 0; j < 4; j++) GLD_LDS16(bp[j] + kb*BKK, BsB + (w*4 + j)*1024);
    __syncthreads();
    #pragma unroll
    for (int ks = 0; ks < 2; ks++){
      int c = (ks*4 + q) ^ mx;
      short8 a[4], b[4];
      #pragma unroll
      for (int mi = 0; mi < 4; mi++) a[mi] = Ar[(wm*64 + mi*16 + ml)*8 + c];
      #pragma unroll
      for (int ni = 0; ni < 4; ni++) b[ni] = Br[(wn*64 + ni*16 + ml)*8 + c];
      #pragma unroll
      for (int mi = 0; mi < 4; mi++){
        #pragma unroll
        for (int ni = 0; ni < 4; ni++)
          acc[mi][ni] = __builtin_amdgcn_mfma_f32_16x16x32_bf16(a[mi], b[ni], acc[mi][ni], 0, 0, 0);
      }
    }
    __syncthreads();
  }

  #pragma unroll
  for (int ni = 0; ni < 4; ni++){
    int d = nb*TN + wn*64 + ni*16 + ml;
    float bb = b2[e*DIM + d];
    #pragma unroll
    for (int mi = 0; mi < 4; mi++){
      #pragma unroll
      for (int r = 0; r < 4; r++){
        int m = wm*64 + mi*16 + q*4 + r;
        Yp[(size_t)(rowbase + m) * DIM + d] = f2bf(acc[mi][ni][r] + bb);
      }
    }
  }
}

// ---------------- combine: out = g0*y0 + g1*y1 ------------------------------
__global__ __launch_bounds__(256) void combine_kernel(
    const short* __restrict__ Yp, const int* __restrict__ tok2row,
    const float* __restrict__ gatev, float* __restrict__ out)
{
  int idx = blockIdx.x * 256 + threadIdx.x;   // over N_TOK * (DIM/8)
  int t = idx >> 7, d8 = idx & 127;
  int r0 = tok2row[t*2], r1 = tok2row[t*2 + 1];
  float g0 = gatev[t*2], g1 = gatev[t*2 + 1];
  short8 y0 = *(const short8*)(Yp + (size_t)r0 * DIM + d8*8);
  short8 y1 = *(const short8*)(Yp + (size_t)r1 * DIM + d8*8);
  float o[8];
  #pragma unroll
  for (int j = 0; j < 8; j++) o[j] = g0 * bf2f(y0[j]) + g1 * bf2f(y1[j]);
  f32x4 v0 = {o[0], o[1], o[2], o[3]};
  f32x4 v1 = {o[4], o[5], o[6], o[7]};
  f32x4* dst = (f32x4*)(out + (size_t)t * DIM + d8*8);
  dst[0] = v0; dst[1] = v1;
}

// ---------------- launch ----------------------------------------------------
extern "C" void kernel_launch(void* const* d_in, const int* in_sizes, int n_in,
                              void* d_out, int out_size, void* d_ws, size_t ws_size,
                              hipStream_t stream)
{
  const float* x  = (const float*)d_in[0];
  const float* gw = (const float*)d_in[1];
  const float* w1 = (const float*)d_in[2];
  const float* b1 = (const float*)d_in[3];
  const float* w2 = (const float*)d_in[4];
  const float* b2 = (const float*)d_in[5];
  float* out = (float*)d_out;

  char* ws = (char*)d_ws;
  size_t o = 0;
  int*   ctrl    = (int*)(ws + o); o += 256;
  int*   topi    = (int*)(ws + o); o += (size_t)N_TOK*2*4;
  float* gatev   = (float*)(ws + o); o += (size_t)N_TOK*2*4;
  int*   rowTok  = (int*)(ws + o); o += (size_t)RCAP*4;
  int*   tok2row = (int*)(ws + o); o += (size_t)N_TOK*2*4;
  int*   tileE   = (int*)(ws + o); o += 1024;
  int*   tileR   = (int*)(ws + o); o += 1024;
  o = (o + 255) & ~(size_t)255;
  short* Xb  = (short*)(ws + o); o += (size_t)(N_TOK + 1)*DIM*2;
  short* W1t = (short*)(ws + o); o += (size_t)NE*DIM*NF*2;
  short* W2t = (short*)(ws + o); o += (size_t)NE*NF*DIM*2;
  short* H   = (short*)(ws + o); o += (size_t)RCAP*NF*2;
  short* Yp  = (short*)(ws + o); o += (size_t)RCAP*DIM*2;
  (void)in_sizes; (void)n_in; (void)out_size;

  if (o > ws_size) return;   // clean bail (diagnostic) instead of OOB crash

  hipMemsetAsync(ctrl, 0, 256, stream);
  gate_kernel<<<N_TOK/4, 256, 0, stream>>>(x, gw, topi, gatev, ctrl);
  scan_kernel<<<1, 64, 0, stream>>>(ctrl, tileE, tileR);
  scatter_kernel<<<N_TOK/256, 256, 0, stream>>>(topi, ctrl, rowTok, tok2row);
  pad_kernel<<<NE, 128, 0, stream>>>(ctrl, rowTok);
  cast_x_kernel<<<((N_TOK + 1)*DIM/8 + 255)/256, 256, 0, stream>>>(x, Xb);
  transpose_cast_kernel<<<dim3(NF/64, DIM/64, NE), 256, 0, stream>>>(w1, W1t, DIM, NF);
  transpose_cast_kernel<<<dim3(DIM/64, NF/64, NE), 256, 0, stream>>>(w2, W2t, NF, DIM);
  ffn1_kernel<<<dim3(NF/TN, MTL), 256, 0, stream>>>(Xb, W1t, b1, ctrl, tileE, tileR, rowTok, H);
  ffn2_kernel<<<dim3(DIM/TN, MTL), 256, 0, stream>>>(H, W2t, b2, ctrl, tileE, tileR, Yp);
  combine_kernel<<<N_TOK*(DIM/8)/256, 256, 0, stream>>>(Yp, tok2row, gatev, out);
}